// Round 12
// baseline (239.040 us; speedup 1.0000x reference)
//
#include <hip/hip_runtime.h>
#include <hip/hip_bf16.h>
#include <math.h>
#include <stdint.h>

// ---------------------------------------------------------------------------
// MoCo contrastive: loss + queue update.  B=1024 D=2048 H=1024 M=256 Q=65536
// NNEG=16384, T=0.07.
// Round 17: R11 falsified store-alignment (WRITE_SIZE unchanged 90.75MB,
// perf worse from misaligned loads).  Revert to R10 structure (best, 215.4)
// EXCEPT: the 64MB queue copy goes through hipMemcpyAsync D2D (rocclr blit,
// the same optimized family as the 6.5 TB/s fills) instead of our kernel
// copy which plateaued at 2.3-3.1 TB/s across 6 shapes/pairings.
// prep_all = casts + transpose + gather only.
// ---------------------------------------------------------------------------

typedef __attribute__((ext_vector_type(4))) float floatx4;
typedef __attribute__((ext_vector_type(8))) short bf16x8;   // 8 bf16 = 4 VGPRs
typedef __attribute__((ext_vector_type(8))) unsigned short ushort8;

__device__ __forceinline__ unsigned short f2bf(float x) {
    union { float f; unsigned int u; } v; v.f = x;
    unsigned int r = v.u + 0x7FFFu + ((v.u >> 16) & 1u);
    return (unsigned short)(r >> 16);
}

__device__ __forceinline__ void async_cp16(const void* g, void* l) {
    auto gp = reinterpret_cast<const __attribute__((address_space(1))) unsigned int*>(
        reinterpret_cast<uintptr_t>(g));
    auto lp = reinterpret_cast<__attribute__((address_space(3))) unsigned int*>(
        reinterpret_cast<uintptr_t>(l));
    __builtin_amdgcn_global_load_lds(gp, lp, 16, 0, 0);
}

// ---------------------------------------------------------------------------
// prep_all (R6/R8-proven): bf16 casts (4096) + Wp transpose (256) +
// gather+l2norm (256).
// ---------------------------------------------------------------------------
__global__ __launch_bounds__(256) void prep_all(
    const float* __restrict__ y2, const float* __restrict__ y1,
    const float* __restrict__ Wq, const float* __restrict__ Wk,
    const float* __restrict__ Wp,
    unsigned short* __restrict__ y2b, unsigned short* __restrict__ y1b,
    unsigned short* __restrict__ Wqb, unsigned short* __restrict__ Wkb,
    unsigned short* __restrict__ Wpt,
    const float* __restrict__ queue, const int* __restrict__ sidx,
    unsigned short* __restrict__ negb,
    int D, int H, int M) {
    __shared__ unsigned short tile[32][33];
    const int b = blockIdx.x, t = threadIdx.x;

    if (b < 4096) {                    // bf16 casts, 8 elems/thread
        const int g = b >> 10, i = b & 1023;
        const float* in = (g == 0) ? y2 : (g == 1) ? y1 : (g == 2) ? Wq : Wk;
        unsigned short* outp = (g == 0) ? y2b : (g == 1) ? y1b : (g == 2) ? Wqb : Wkb;
        long idx = (long)i * 256 + t;
        const float4* in4 = (const float4*)in;
        float4 a = in4[idx * 2], c = in4[idx * 2 + 1];
        ushort8 o;
        o[0] = f2bf(a.x); o[1] = f2bf(a.y); o[2] = f2bf(a.z); o[3] = f2bf(a.w);
        o[4] = f2bf(c.x); o[5] = f2bf(c.y); o[6] = f2bf(c.z); o[7] = f2bf(c.w);
        ((ushort8*)outp)[idx] = o;
        return;
    }
    if (b < 4352) {                    // Wp [H][M] f32 -> Wpt [M][H] bf16
        int idx = b - 4096;
        const int R = H, C = M;
        int cb = C / 32;
        int c0 = (idx % cb) * 32, r0 = (idx / cb) * 32;
        int tx = t & 31, ty = t >> 5;
#pragma unroll
        for (int i = 0; i < 4; ++i)
            tile[ty + i * 8][tx] = f2bf(Wp[(size_t)(r0 + ty + i * 8) * C + c0 + tx]);
        __syncthreads();
#pragma unroll
        for (int i = 0; i < 4; ++i)
            Wpt[(size_t)(c0 + ty + i * 8) * R + r0 + tx] = tile[tx][ty + i * 8];
        return;
    }
    // gather+l2norm, gid in [0,256), 64 rows each
    const int gid = b - 4352;
    const int w = t >> 6, lane = t & 63;
#pragma unroll
    for (int j = 0; j < 16; ++j) {
        int r = gid * 64 + w * 16 + j;
        const float4* src = (const float4*)(queue + (size_t)sidx[r] * 256);
        float4 v = src[lane];
        float ss = v.x * v.x + v.y * v.y + v.z * v.z + v.w * v.w;
#pragma unroll
        for (int off = 1; off < 64; off <<= 1) ss += __shfl_xor(ss, off);
        float inv = 1.f / fmaxf(sqrtf(ss), 1e-12f);
        unsigned short o[4] = { f2bf(v.x * inv), f2bf(v.y * inv),
                                f2bf(v.z * inv), f2bf(v.w * inv) };
        *(unsigned long long*)(negb + (size_t)r * 256 + lane * 4) =
            *(unsigned long long*)o;
    }
}

// ---------------------------------------------------------------------------
// wc_gemm: 128 blocks, pure Wc GEMM (R4/R6-proven).
// ---------------------------------------------------------------------------
__global__ __launch_bounds__(256) void wc_gemm(
    const unsigned short* __restrict__ Wpt,   // [256][1024]
    const unsigned short* __restrict__ Wqkb,  // Wqb|Wkb (stride D*H)
    unsigned short* __restrict__ Wct) {       // [2][256][2048] bf16
    __shared__ unsigned short As[3][128 * 32];
    __shared__ unsigned short Bs[3][64 * 32];
    const int id = blockIdx.x, t = threadIdx.x;
    const int batch = id >> 6, rem = id & 63;
    const int row0 = (rem >> 5) * 128;        // m-tile: 0 or 128
    const int col0 = (rem & 31) * 64;         // d-tile: 32 of them
    const unsigned short* A = Wpt;
    const unsigned short* Bp = Wqkb + (long)batch * 2048 * 1024;
    unsigned short* C = Wct + (long)batch * 256 * 2048;
    const int Ko = 1024, No = 2048, nIt = 32;
    const int lane = t & 63, wave = t >> 6;
    const int wr = wave >> 1, wc = wave & 1;
    const int lrow = lane & 15, quad = lane >> 4;

    floatx4 acc[4][2] = {};

    auto stage = [&](int kk, int p) {
        int c0 = t, c1 = t + 256;
        async_cp16(A + (size_t)(row0 + (c0 >> 2)) * Ko + kk + (((c0 & 3) ^ ((c0 >> 2) & 3))) * 8,
                   (char*)(As[p]) + (size_t)c0 * 16);
        async_cp16(A + (size_t)(row0 + (c1 >> 2)) * Ko + kk + (((c1 & 3) ^ ((c1 >> 2) & 3))) * 8,
                   (char*)(As[p]) + (size_t)c1 * 16);
        async_cp16(Bp + (size_t)(col0 + (t >> 2)) * Ko + kk + (((t & 3) ^ ((t >> 2) & 3))) * 8,
                   (char*)(Bs[p]) + (size_t)t * 16);
    };
    auto compute = [&](int p) {
        bf16x8 af[4], bfr[2];
#pragma unroll
        for (int i = 0; i < 4; ++i) {
            int row = wr * 64 + i * 16 + lrow;
            af[i] = *(const bf16x8*)(As[p] + (size_t)row * 32 + (quad ^ (row & 3)) * 8);
        }
#pragma unroll
        for (int j = 0; j < 2; ++j) {
            int row = wc * 32 + j * 16 + lrow;
            bfr[j] = *(const bf16x8*)(Bs[p] + (size_t)row * 32 + (quad ^ (row & 3)) * 8);
        }
        __builtin_amdgcn_s_setprio(1);
#pragma unroll
        for (int i = 0; i < 4; ++i)
#pragma unroll
            for (int j = 0; j < 2; ++j)
                acc[i][j] = __builtin_amdgcn_mfma_f32_16x16x32_bf16(af[i], bfr[j], acc[i][j], 0, 0, 0);
        __builtin_amdgcn_s_setprio(0);
    };

    stage(0, 0);
    stage(32, 1);
    for (int k = 0; k < nIt; ++k) {
        if (k + 2 < nIt) {
            stage((k + 2) * 32, (k + 2) % 3);
            asm volatile("s_waitcnt vmcnt(6)" ::: "memory");
        } else if (k + 2 == nIt) {
            asm volatile("s_waitcnt vmcnt(3)" ::: "memory");
        } else {
            asm volatile("s_waitcnt vmcnt(0)" ::: "memory");
        }
        __builtin_amdgcn_s_barrier();
        compute(k % 3);
        __builtin_amdgcn_s_barrier();
    }
#pragma unroll
    for (int i = 0; i < 4; ++i) {
        int grow = row0 + wr * 64 + i * 16 + quad * 4;
#pragma unroll
        for (int j = 0; j < 2; ++j) {
            int gcol = col0 + wc * 32 + j * 16 + lrow;
#pragma unroll
            for (int r = 0; r < 4; ++r)
                C[(size_t)(grow + r) * No + gcol] = f2bf(acc[i][j][r]);
        }
    }
}

// ---------------------------------------------------------------------------
// qk_gemm: 512 blocks, BM=64 BN=64 BK=32, pure (R4/R7-proven).
// ---------------------------------------------------------------------------
__global__ __launch_bounds__(256) void qk_gemm(
    const unsigned short* __restrict__ Yb,    // y2b|y1b (stride B*D)
    const unsigned short* __restrict__ Wct,   // [2][256][2048]
    float* __restrict__ Pg) {                 // [8][1024][256] fp32
    __shared__ unsigned short As[3][64 * 32];
    __shared__ unsigned short Bs[3][64 * 32];
    const int id = blockIdx.x, t = threadIdx.x;
    const int z = id >> 6, rem = id & 63;
    const int batch = z >> 2, split = z & 3;
    const int row0 = (rem >> 2) * 64;         // b-tile: 16 of them
    const int col0 = (rem & 3) * 64;          // m-tile: 4 of them
    const unsigned short* A = Yb + (long)batch * 1024 * 2048;
    const unsigned short* Bp = Wct + (long)batch * 256 * 2048;
    float* P = Pg + (long)z * 1024 * 256;
    const int Ko = 2048, No = 256, nIt = 16;
    const int kbeg = split * 512;
    const int lane = t & 63, wave = t >> 6;
    const int wr = wave >> 1, wc = wave & 1;
    const int lrow = lane & 15, quad = lane >> 4;

    floatx4 acc[2][2] = {};

    auto stage = [&](int kk, int p) {
        async_cp16(A + (size_t)(row0 + (t >> 2)) * Ko + kk + (((t & 3) ^ ((t >> 2) & 3))) * 8,
                   (char*)(As[p]) + (size_t)t * 16);
        async_cp16(Bp + (size_t)(col0 + (t >> 2)) * Ko + kk + (((t & 3) ^ ((t >> 2) & 3))) * 8,
                   (char*)(Bs[p]) + (size_t)t * 16);
    };
    auto compute = [&](int p) {
        bf16x8 af[2], bfr[2];
#pragma unroll
        for (int i = 0; i < 2; ++i) {
            int row = wr * 32 + i * 16 + lrow;
            af[i] = *(const bf16x8*)(As[p] + (size_t)row * 32 + (quad ^ (row & 3)) * 8);
        }
#pragma unroll
        for (int j = 0; j < 2; ++j) {
            int row = wc * 32 + j * 16 + lrow;
            bfr[j] = *(const bf16x8*)(Bs[p] + (size_t)row * 32 + (quad ^ (row & 3)) * 8);
        }
        __builtin_amdgcn_s_setprio(1);
#pragma unroll
        for (int i = 0; i < 2; ++i)
#pragma unroll
            for (int j = 0; j < 2; ++j)
                acc[i][j] = __builtin_amdgcn_mfma_f32_16x16x32_bf16(af[i], bfr[j], acc[i][j], 0, 0, 0);
        __builtin_amdgcn_s_setprio(0);
    };

    stage(kbeg, 0);
    stage(kbeg + 32, 1);
    for (int k = 0; k < nIt; ++k) {
        if (k + 2 < nIt) {
            stage(kbeg + (k + 2) * 32, (k + 2) % 3);
            asm volatile("s_waitcnt vmcnt(4)" ::: "memory");
        } else if (k + 2 == nIt) {
            asm volatile("s_waitcnt vmcnt(2)" ::: "memory");
        } else {
            asm volatile("s_waitcnt vmcnt(0)" ::: "memory");
        }
        __builtin_amdgcn_s_barrier();
        compute(k % 3);
        __builtin_amdgcn_s_barrier();
    }
#pragma unroll
    for (int i = 0; i < 2; ++i) {
        int grow = row0 + wr * 32 + i * 16 + quad * 4;
#pragma unroll
        for (int j = 0; j < 2; ++j) {
            int gcol = col0 + wc * 32 + j * 16 + lrow;
#pragma unroll
            for (int r = 0; r < 4; ++r)
                P[(size_t)(grow + r) * No + gcol] = acc[i][j][r];
        }
    }
}

// reduce proj partials + l2norm + bf16 cast + pos/sumexp + scatter k rows.
// Scatter ordered after the memcpy copy (dispatch 1); dword stores.
__global__ __launch_bounds__(256) void qk_finalize(const float* __restrict__ P,
                                                   const int* __restrict__ widx,
                                                   unsigned short* __restrict__ qkb,
                                                   float* __restrict__ newq,
                                                   float* __restrict__ pos,
                                                   float* __restrict__ sumexp,
                                                   int B_, int nsplit, float invT) {
    const int i = blockIdx.x, t = threadIdx.x;
    const long RM = (long)B_ * 256;
    float sq = 0.f, sk = 0.f;
    for (int s = 0; s < nsplit; ++s) {
        sq += P[(long)s * RM + (long)i * 256 + t];
        sk += P[(long)(nsplit + s) * RM + (long)i * 256 + t];
    }
    __shared__ float r0[256], r1[256], r2[256];
    r0[t] = sq * sq; r1[t] = sk * sk; r2[t] = sq * sk;
    __syncthreads();
    for (int off = 128; off > 0; off >>= 1) {
        if (t < off) { r0[t] += r0[t + off]; r1[t] += r1[t + off]; r2[t] += r2[t + off]; }
        __syncthreads();
    }
    float nq = fmaxf(sqrtf(r0[0]), 1e-12f);
    float nk = fmaxf(sqrtf(r1[0]), 1e-12f);
    float qn = sq / nq, kn = sk / nk;
    qkb[(size_t)i * 256 + t] = f2bf(qn);
    qkb[(size_t)(B_ + i) * 256 + t] = f2bf(kn);
    newq[(size_t)widx[i] * 256 + t] = kn;
    if (t == 0) {
        float p = (r2[0] / (nq * nk)) * invT;
        pos[i] = p;
        sumexp[i] = __expf(p);
    }
}

// ---------------------------------------------------------------------------
// Fused logits GEMM (R4/R6-proven, swizzled).
// ---------------------------------------------------------------------------
__global__ __launch_bounds__(256) void gemm_logits(const unsigned short* __restrict__ A,
                                                   const unsigned short* __restrict__ B,
                                                   float* __restrict__ sumexp,
                                                   int Ko, float invT) {
    __shared__ unsigned short As[128 * 64];
    __shared__ unsigned short Bs[128 * 64];
    __shared__ float rowred[128];
    const int row0 = blockIdx.y * 128, col0 = blockIdx.x * 128;
    const int t = threadIdx.x;
    const int lane = t & 63, wave = t >> 6;
    const int wr = wave >> 1, wc = wave & 1;
    const int lrow = lane & 15, quad = lane >> 4;

    floatx4 acc[4][4] = {};

    for (int kk = 0; kk < Ko; kk += 64) {
#pragma unroll
        for (int r = 0; r < 4; ++r) {
            int c = t + r * 256;
            int srcchunk = (c & 7) ^ ((c >> 3) & 7);
            async_cp16(A + (size_t)(row0 + (c >> 3)) * Ko + kk + srcchunk * 8,
                       (char*)As + (size_t)c * 16);
            async_cp16(B + (size_t)(col0 + (c >> 3)) * Ko + kk + srcchunk * 8,
                       (char*)Bs + (size_t)c * 16);
        }
        __syncthreads();
        bf16x8 af[4][2], bf[4][2];
#pragma unroll
        for (int i = 0; i < 4; ++i)
#pragma unroll
            for (int k2 = 0; k2 < 2; ++k2) {
                int rowa = wr * 64 + i * 16 + lrow;
                int rowb = wc * 64 + i * 16 + lrow;
                af[i][k2] = *(const bf16x8*)(As + (size_t)rowa * 64 + ((k2 * 4 + quad) ^ (rowa & 7)) * 8);
                bf[i][k2] = *(const bf16x8*)(Bs + (size_t)rowb * 64 + ((k2 * 4 + quad) ^ (rowb & 7)) * 8);
            }
#pragma unroll
        for (int k2 = 0; k2 < 2; ++k2)
#pragma unroll
            for (int i = 0; i < 4; ++i)
#pragma unroll
                for (int j = 0; j < 4; ++j)
                    acc[i][j] = __builtin_amdgcn_mfma_f32_16x16x32_bf16(af[i][k2], bf[j][k2], acc[i][j], 0, 0, 0);
        __syncthreads();
    }
    if (t < 128) rowred[t] = 0.f;
    __syncthreads();
#pragma unroll
    for (int i = 0; i < 4; ++i) {
#pragma unroll
        for (int r = 0; r < 4; ++r) {
            float s = 0.f;
#pragma unroll
            for (int j = 0; j < 4; ++j) s += __expf(acc[i][j][r] * invT);
            s += __shfl_xor(s, 1); s += __shfl_xor(s, 2);
            s += __shfl_xor(s, 4); s += __shfl_xor(s, 8);
            if (lrow == 0) atomicAdd(&rowred[wr * 64 + i * 16 + quad * 4 + r], s);
        }
    }
    __syncthreads();
    if (t < 128) atomicAdd(&sumexp[row0 + t], rowred[t]);
}

__global__ __launch_bounds__(256) void final_loss(const float* __restrict__ pos,
                                                  const float* __restrict__ sumexp,
                                                  float* __restrict__ out, int B_) {
    const int t = threadIdx.x;
    float acc = 0.f;
    for (int i = t; i < B_; i += 256) acc += logf(sumexp[i]) - pos[i];
    __shared__ float s[256];
    s[t] = acc;
    __syncthreads();
    for (int off = 128; off > 0; off >>= 1) {
        if (t < off) s[t] += s[t + off];
        __syncthreads();
    }
    if (t == 0) out[0] = s[0] / (float)B_;
}

extern "C" void kernel_launch(void* const* d_in, const int* in_sizes, int n_in,
                              void* d_out, int out_size, void* d_ws, size_t ws_size,
                              hipStream_t stream) {
    const float* y1    = (const float*)d_in[0];
    const float* y2    = (const float*)d_in[1];
    const float* Wq    = (const float*)d_in[2];
    const float* Wk    = (const float*)d_in[3];
    const float* Wp    = (const float*)d_in[4];
    const float* queue = (const float*)d_in[5];
    const int*   sidx  = (const int*)d_in[6];
    const int*   widx  = (const int*)d_in[7];
    float* out = (float*)d_out;

    const int B    = in_sizes[7];              // 1024
    const int NNEG = in_sizes[6];              // 16384
    const int D    = in_sizes[0] / B;          // 2048
    const int H    = in_sizes[2] / D;          // 1024
    const int M    = in_sizes[4] / H;          // 256
    const int Q    = in_sizes[5] / M;          // 65536
    const float invT = 1.0f / 0.07f;
    const int NS_P = 4;

    // ---- workspace layout (identical to R4..R11, which passed) ----
    float* ws  = (float*)d_ws;
    float* Pp     = ws;                              // [2*NS_P][B*M] = 2M floats
    float* pos    = Pp + (size_t)2 * NS_P * B * M;
    float* sumexp = pos + B;
    unsigned short* us = (unsigned short*)(sumexp + B);
    unsigned short* y2b  = us;                       // B*D   (y2b|y1b contiguous)
    unsigned short* y1b  = y2b + (size_t)B * D;      // B*D
    unsigned short* Wqb  = y1b + (size_t)B * D;      // D*H   (Wqb|Wkb contiguous)
    unsigned short* Wkb  = Wqb + (size_t)D * H;      // D*H
    unsigned short* Wpt  = Wkb + (size_t)D * H;      // M*H
    unsigned short* Wct  = Wpt + (size_t)M * H;      // [2][M][D] bf16
    unsigned short* qkb  = Wct + (size_t)2 * M * D;  // 2*B*M
    unsigned short* negb = qkb + (size_t)2 * B * M;  // NNEG*M

    // 1. queue -> new_queue via the runtime's blit path (rocclr copy kernel,
    //    same optimized family as the 6.5 TB/s fills).  Stream-ordered, so
    //    the widx scatter in qk_finalize (dispatch 5) stays correct.
    hipMemcpyAsync(out + 1, queue, (size_t)Q * M * sizeof(float),
                   hipMemcpyDeviceToDevice, stream);

    // 2. casts + transpose + gather
    const int nPrep = 4 * 1024 + (H / 32) * (M / 32) + NNEG / 64;
    prep_all<<<nPrep, 256, 0, stream>>>(y2, y1, Wq, Wk, Wp,
                                        y2b, y1b, Wqb, Wkb, Wpt,
                                        queue, sidx, negb, D, H, M);

    // 3. Wc^T GEMM, uncontended
    wc_gemm<<<128, 256, 0, stream>>>(Wpt, Wqb, Wct);

    // 4. qk projection GEMM (K-split 4, fp32 partials), pure
    qk_gemm<<<512, 256, 0, stream>>>(y2b, Wct, Pp);

    // 5. fused reduce + l2norm + cast + pos/sumexp + scatter k
    qk_finalize<<<B, 256, 0, stream>>>(Pp, widx, qkb, out + 1, pos, sumexp,
                                       B, NS_P, invT);

    // 6. fused negative logits + exp + row-sum
    gemm_logits<<<dim3(NNEG / 128, B / 128), 256, 0, stream>>>(
        qkb, negb, sumexp, M, invT);

    // 7. loss
    final_loss<<<1, 256, 0, stream>>>(pos, sumexp, out, B);
}

// Round 13
// 215.314 us; speedup vs baseline: 1.1102x; 1.1102x over previous
//
#include <hip/hip_runtime.h>
#include <hip/hip_bf16.h>
#include <math.h>
#include <stdint.h>

// ---------------------------------------------------------------------------
// MoCo contrastive: loss + queue update.  B=1024 D=2048 H=1024 M=256 Q=65536
// NNEG=16384, T=0.07.
// Round 18: REVERT to R10 (best measured, 215.4us).  R12 closed the copy
// investigation: vendor blit = 1.9 TB/s on this dst, our kernels = 2.3-3.1,
// fills (write-only) = 6.5 -- the read+write stream wall is implementation-
// independent.  R10's merged streaming dispatch is the best arrangement.
// Ledger: ~123us harness fills + ~52us merged streaming (copy-wall) +
// ~18us GEMM/finalize/loss (each near own roofline) + ~12us gaps = ~215us.
// ---------------------------------------------------------------------------

typedef __attribute__((ext_vector_type(4))) float floatx4;
typedef __attribute__((ext_vector_type(8))) short bf16x8;   // 8 bf16 = 4 VGPRs
typedef __attribute__((ext_vector_type(8))) unsigned short ushort8;

__device__ __forceinline__ unsigned short f2bf(float x) {
    union { float f; unsigned int u; } v; v.f = x;
    unsigned int r = v.u + 0x7FFFu + ((v.u >> 16) & 1u);
    return (unsigned short)(r >> 16);
}

__device__ __forceinline__ void async_cp16(const void* g, void* l) {
    auto gp = reinterpret_cast<const __attribute__((address_space(1))) unsigned int*>(
        reinterpret_cast<uintptr_t>(g));
    auto lp = reinterpret_cast<__attribute__((address_space(3))) unsigned int*>(
        reinterpret_cast<uintptr_t>(l));
    __builtin_amdgcn_global_load_lds(gp, lp, 16, 0, 0);
}

// ---------------------------------------------------------------------------
// prep_all: ALL pure-streaming work, one dispatch (R10-proven, best):
//   [0,4096)     bf16 casts of y2,y1,Wq,Wk
//   [4096,4352)  Wp [H][M] -> Wpt [M][H] bf16 transpose
//   [4352,4608)  gather+l2norm negatives (64 rows/block)
//   [4608,6656)  queue -> new_queue dword-granular copy (2048 blocks,
//                256 thr x 32 floats, dst = out+1 is 4B-aligned only)
// ---------------------------------------------------------------------------
__global__ __launch_bounds__(256) void prep_all(
    const float* __restrict__ y2, const float* __restrict__ y1,
    const float* __restrict__ Wq, const float* __restrict__ Wk,
    const float* __restrict__ Wp,
    unsigned short* __restrict__ y2b, unsigned short* __restrict__ y1b,
    unsigned short* __restrict__ Wqb, unsigned short* __restrict__ Wkb,
    unsigned short* __restrict__ Wpt,
    const float* __restrict__ queue, const int* __restrict__ sidx,
    unsigned short* __restrict__ negb,
    float* __restrict__ newq,
    int D, int H, int M) {
    __shared__ unsigned short tile[32][33];
    const int b = blockIdx.x, t = threadIdx.x;

    if (b < 4096) {                    // bf16 casts, 8 elems/thread
        const int g = b >> 10, i = b & 1023;
        const float* in = (g == 0) ? y2 : (g == 1) ? y1 : (g == 2) ? Wq : Wk;
        unsigned short* outp = (g == 0) ? y2b : (g == 1) ? y1b : (g == 2) ? Wqb : Wkb;
        long idx = (long)i * 256 + t;
        const float4* in4 = (const float4*)in;
        float4 a = in4[idx * 2], c = in4[idx * 2 + 1];
        ushort8 o;
        o[0] = f2bf(a.x); o[1] = f2bf(a.y); o[2] = f2bf(a.z); o[3] = f2bf(a.w);
        o[4] = f2bf(c.x); o[5] = f2bf(c.y); o[6] = f2bf(c.z); o[7] = f2bf(c.w);
        ((ushort8*)outp)[idx] = o;
        return;
    }
    if (b < 4352) {                    // Wp [H][M] f32 -> Wpt [M][H] bf16
        int idx = b - 4096;
        const int R = H, C = M;
        int cb = C / 32;
        int c0 = (idx % cb) * 32, r0 = (idx / cb) * 32;
        int tx = t & 31, ty = t >> 5;
#pragma unroll
        for (int i = 0; i < 4; ++i)
            tile[ty + i * 8][tx] = f2bf(Wp[(size_t)(r0 + ty + i * 8) * C + c0 + tx]);
        __syncthreads();
#pragma unroll
        for (int i = 0; i < 4; ++i)
            Wpt[(size_t)(c0 + ty + i * 8) * R + r0 + tx] = tile[tx][ty + i * 8];
        return;
    }
    if (b < 4608) {                    // gather+l2norm, 64 rows each
        const int gid = b - 4352;
        const int w = t >> 6, lane = t & 63;
#pragma unroll
        for (int j = 0; j < 16; ++j) {
            int r = gid * 64 + w * 16 + j;
            const float4* src = (const float4*)(queue + (size_t)sidx[r] * 256);
            float4 v = src[lane];
            float ss = v.x * v.x + v.y * v.y + v.z * v.z + v.w * v.w;
#pragma unroll
            for (int off = 1; off < 64; off <<= 1) ss += __shfl_xor(ss, off);
            float inv = 1.f / fmaxf(sqrtf(ss), 1e-12f);
            unsigned short o[4] = { f2bf(v.x * inv), f2bf(v.y * inv),
                                    f2bf(v.z * inv), f2bf(v.w * inv) };
            *(unsigned long long*)(negb + (size_t)r * 256 + lane * 4) =
                *(unsigned long long*)o;
        }
        return;
    }
    // queue copy, cid in [0,2048), dword-granular, 32 floats/thread
    const int cid = b - 4608;
    const long base = (long)cid * 8192 + t;
    float v[32];
#pragma unroll
    for (int i = 0; i < 32; ++i) v[i] = queue[base + (long)i * 256];
#pragma unroll
    for (int i = 0; i < 32; ++i) newq[base + (long)i * 256] = v[i];
}

// ---------------------------------------------------------------------------
// wc_gemm: 128 blocks, pure Wc GEMM (R4/R6-proven).
// ---------------------------------------------------------------------------
__global__ __launch_bounds__(256) void wc_gemm(
    const unsigned short* __restrict__ Wpt,   // [256][1024]
    const unsigned short* __restrict__ Wqkb,  // Wqb|Wkb (stride D*H)
    unsigned short* __restrict__ Wct) {       // [2][256][2048] bf16
    __shared__ unsigned short As[3][128 * 32];
    __shared__ unsigned short Bs[3][64 * 32];
    const int id = blockIdx.x, t = threadIdx.x;
    const int batch = id >> 6, rem = id & 63;
    const int row0 = (rem >> 5) * 128;        // m-tile: 0 or 128
    const int col0 = (rem & 31) * 64;         // d-tile: 32 of them
    const unsigned short* A = Wpt;
    const unsigned short* Bp = Wqkb + (long)batch * 2048 * 1024;
    unsigned short* C = Wct + (long)batch * 256 * 2048;
    const int Ko = 1024, No = 2048, nIt = 32;
    const int lane = t & 63, wave = t >> 6;
    const int wr = wave >> 1, wc = wave & 1;
    const int lrow = lane & 15, quad = lane >> 4;

    floatx4 acc[4][2] = {};

    auto stage = [&](int kk, int p) {
        int c0 = t, c1 = t + 256;
        async_cp16(A + (size_t)(row0 + (c0 >> 2)) * Ko + kk + (((c0 & 3) ^ ((c0 >> 2) & 3))) * 8,
                   (char*)(As[p]) + (size_t)c0 * 16);
        async_cp16(A + (size_t)(row0 + (c1 >> 2)) * Ko + kk + (((c1 & 3) ^ ((c1 >> 2) & 3))) * 8,
                   (char*)(As[p]) + (size_t)c1 * 16);
        async_cp16(Bp + (size_t)(col0 + (t >> 2)) * Ko + kk + (((t & 3) ^ ((t >> 2) & 3))) * 8,
                   (char*)(Bs[p]) + (size_t)t * 16);
    };
    auto compute = [&](int p) {
        bf16x8 af[4], bfr[2];
#pragma unroll
        for (int i = 0; i < 4; ++i) {
            int row = wr * 64 + i * 16 + lrow;
            af[i] = *(const bf16x8*)(As[p] + (size_t)row * 32 + (quad ^ (row & 3)) * 8);
        }
#pragma unroll
        for (int j = 0; j < 2; ++j) {
            int row = wc * 32 + j * 16 + lrow;
            bfr[j] = *(const bf16x8*)(Bs[p] + (size_t)row * 32 + (quad ^ (row & 3)) * 8);
        }
        __builtin_amdgcn_s_setprio(1);
#pragma unroll
        for (int i = 0; i < 4; ++i)
#pragma unroll
            for (int j = 0; j < 2; ++j)
                acc[i][j] = __builtin_amdgcn_mfma_f32_16x16x32_bf16(af[i], bfr[j], acc[i][j], 0, 0, 0);
        __builtin_amdgcn_s_setprio(0);
    };

    stage(0, 0);
    stage(32, 1);
    for (int k = 0; k < nIt; ++k) {
        if (k + 2 < nIt) {
            stage((k + 2) * 32, (k + 2) % 3);
            asm volatile("s_waitcnt vmcnt(6)" ::: "memory");
        } else if (k + 2 == nIt) {
            asm volatile("s_waitcnt vmcnt(3)" ::: "memory");
        } else {
            asm volatile("s_waitcnt vmcnt(0)" ::: "memory");
        }
        __builtin_amdgcn_s_barrier();
        compute(k % 3);
        __builtin_amdgcn_s_barrier();
    }
#pragma unroll
    for (int i = 0; i < 4; ++i) {
        int grow = row0 + wr * 64 + i * 16 + quad * 4;
#pragma unroll
        for (int j = 0; j < 2; ++j) {
            int gcol = col0 + wc * 32 + j * 16 + lrow;
#pragma unroll
            for (int r = 0; r < 4; ++r)
                C[(size_t)(grow + r) * No + gcol] = f2bf(acc[i][j][r]);
        }
    }
}

// ---------------------------------------------------------------------------
// qk_gemm: 512 blocks, BM=64 BN=64 BK=32, pure (R4/R7-proven).
// ---------------------------------------------------------------------------
__global__ __launch_bounds__(256) void qk_gemm(
    const unsigned short* __restrict__ Yb,    // y2b|y1b (stride B*D)
    const unsigned short* __restrict__ Wct,   // [2][256][2048]
    float* __restrict__ Pg) {                 // [8][1024][256] fp32
    __shared__ unsigned short As[3][64 * 32];
    __shared__ unsigned short Bs[3][64 * 32];
    const int id = blockIdx.x, t = threadIdx.x;
    const int z = id >> 6, rem = id & 63;
    const int batch = z >> 2, split = z & 3;
    const int row0 = (rem >> 2) * 64;         // b-tile: 16 of them
    const int col0 = (rem & 3) * 64;          // m-tile: 4 of them
    const unsigned short* A = Yb + (long)batch * 1024 * 2048;
    const unsigned short* Bp = Wct + (long)batch * 256 * 2048;
    float* P = Pg + (long)z * 1024 * 256;
    const int Ko = 2048, No = 256, nIt = 16;
    const int kbeg = split * 512;
    const int lane = t & 63, wave = t >> 6;
    const int wr = wave >> 1, wc = wave & 1;
    const int lrow = lane & 15, quad = lane >> 4;

    floatx4 acc[2][2] = {};

    auto stage = [&](int kk, int p) {
        async_cp16(A + (size_t)(row0 + (t >> 2)) * Ko + kk + (((t & 3) ^ ((t >> 2) & 3))) * 8,
                   (char*)(As[p]) + (size_t)t * 16);
        async_cp16(Bp + (size_t)(col0 + (t >> 2)) * Ko + kk + (((t & 3) ^ ((t >> 2) & 3))) * 8,
                   (char*)(Bs[p]) + (size_t)t * 16);
    };
    auto compute = [&](int p) {
        bf16x8 af[2], bfr[2];
#pragma unroll
        for (int i = 0; i < 2; ++i) {
            int row = wr * 32 + i * 16 + lrow;
            af[i] = *(const bf16x8*)(As[p] + (size_t)row * 32 + (quad ^ (row & 3)) * 8);
        }
#pragma unroll
        for (int j = 0; j < 2; ++j) {
            int row = wc * 32 + j * 16 + lrow;
            bfr[j] = *(const bf16x8*)(Bs[p] + (size_t)row * 32 + (quad ^ (row & 3)) * 8);
        }
        __builtin_amdgcn_s_setprio(1);
#pragma unroll
        for (int i = 0; i < 2; ++i)
#pragma unroll
            for (int j = 0; j < 2; ++j)
                acc[i][j] = __builtin_amdgcn_mfma_f32_16x16x32_bf16(af[i], bfr[j], acc[i][j], 0, 0, 0);
        __builtin_amdgcn_s_setprio(0);
    };

    stage(kbeg, 0);
    stage(kbeg + 32, 1);
    for (int k = 0; k < nIt; ++k) {
        if (k + 2 < nIt) {
            stage(kbeg + (k + 2) * 32, (k + 2) % 3);
            asm volatile("s_waitcnt vmcnt(4)" ::: "memory");
        } else if (k + 2 == nIt) {
            asm volatile("s_waitcnt vmcnt(2)" ::: "memory");
        } else {
            asm volatile("s_waitcnt vmcnt(0)" ::: "memory");
        }
        __builtin_amdgcn_s_barrier();
        compute(k % 3);
        __builtin_amdgcn_s_barrier();
    }
#pragma unroll
    for (int i = 0; i < 2; ++i) {
        int grow = row0 + wr * 32 + i * 16 + quad * 4;
#pragma unroll
        for (int j = 0; j < 2; ++j) {
            int gcol = col0 + wc * 32 + j * 16 + lrow;
#pragma unroll
            for (int r = 0; r < 4; ++r)
                P[(size_t)(grow + r) * No + gcol] = acc[i][j][r];
        }
    }
}

// reduce proj partials + l2norm + bf16 cast + pos/sumexp + scatter k rows.
// Scatter ordered after the copy (prep_all, dispatch 1); dword stores.
__global__ __launch_bounds__(256) void qk_finalize(const float* __restrict__ P,
                                                   const int* __restrict__ widx,
                                                   unsigned short* __restrict__ qkb,
                                                   float* __restrict__ newq,
                                                   float* __restrict__ pos,
                                                   float* __restrict__ sumexp,
                                                   int B_, int nsplit, float invT) {
    const int i = blockIdx.x, t = threadIdx.x;
    const long RM = (long)B_ * 256;
    float sq = 0.f, sk = 0.f;
    for (int s = 0; s < nsplit; ++s) {
        sq += P[(long)s * RM + (long)i * 256 + t];
        sk += P[(long)(nsplit + s) * RM + (long)i * 256 + t];
    }
    __shared__ float r0[256], r1[256], r2[256];
    r0[t] = sq * sq; r1[t] = sk * sk; r2[t] = sq * sk;
    __syncthreads();
    for (int off = 128; off > 0; off >>= 1) {
        if (t < off) { r0[t] += r0[t + off]; r1[t] += r1[t + off]; r2[t] += r2[t + off]; }
        __syncthreads();
    }
    float nq = fmaxf(sqrtf(r0[0]), 1e-12f);
    float nk = fmaxf(sqrtf(r1[0]), 1e-12f);
    float qn = sq / nq, kn = sk / nk;
    qkb[(size_t)i * 256 + t] = f2bf(qn);
    qkb[(size_t)(B_ + i) * 256 + t] = f2bf(kn);
    newq[(size_t)widx[i] * 256 + t] = kn;
    if (t == 0) {
        float p = (r2[0] / (nq * nk)) * invT;
        pos[i] = p;
        sumexp[i] = __expf(p);
    }
}

// ---------------------------------------------------------------------------
// Fused logits GEMM (R4/R6-proven, swizzled).
// ---------------------------------------------------------------------------
__global__ __launch_bounds__(256) void gemm_logits(const unsigned short* __restrict__ A,
                                                   const unsigned short* __restrict__ B,
                                                   float* __restrict__ sumexp,
                                                   int Ko, float invT) {
    __shared__ unsigned short As[128 * 64];
    __shared__ unsigned short Bs[128 * 64];
    __shared__ float rowred[128];
    const int row0 = blockIdx.y * 128, col0 = blockIdx.x * 128;
    const int t = threadIdx.x;
    const int lane = t & 63, wave = t >> 6;
    const int wr = wave >> 1, wc = wave & 1;
    const int lrow = lane & 15, quad = lane >> 4;

    floatx4 acc[4][4] = {};

    for (int kk = 0; kk < Ko; kk += 64) {
#pragma unroll
        for (int r = 0; r < 4; ++r) {
            int c = t + r * 256;
            int srcchunk = (c & 7) ^ ((c >> 3) & 7);
            async_cp16(A + (size_t)(row0 + (c >> 3)) * Ko + kk + srcchunk * 8,
                       (char*)As + (size_t)c * 16);
            async_cp16(B + (size_t)(col0 + (c >> 3)) * Ko + kk + srcchunk * 8,
                       (char*)Bs + (size_t)c * 16);
        }
        __syncthreads();
        bf16x8 af[4][2], bf[4][2];
#pragma unroll
        for (int i = 0; i < 4; ++i)
#pragma unroll
            for (int k2 = 0; k2 < 2; ++k2) {
                int rowa = wr * 64 + i * 16 + lrow;
                int rowb = wc * 64 + i * 16 + lrow;
                af[i][k2] = *(const bf16x8*)(As + (size_t)rowa * 64 + ((k2 * 4 + quad) ^ (rowa & 7)) * 8);
                bf[i][k2] = *(const bf16x8*)(Bs + (size_t)rowb * 64 + ((k2 * 4 + quad) ^ (rowb & 7)) * 8);
            }
#pragma unroll
        for (int k2 = 0; k2 < 2; ++k2)
#pragma unroll
            for (int i = 0; i < 4; ++i)
#pragma unroll
                for (int j = 0; j < 4; ++j)
                    acc[i][j] = __builtin_amdgcn_mfma_f32_16x16x32_bf16(af[i][k2], bf[j][k2], acc[i][j], 0, 0, 0);
        __syncthreads();
    }
    if (t < 128) rowred[t] = 0.f;
    __syncthreads();
#pragma unroll
    for (int i = 0; i < 4; ++i) {
#pragma unroll
        for (int r = 0; r < 4; ++r) {
            float s = 0.f;
#pragma unroll
            for (int j = 0; j < 4; ++j) s += __expf(acc[i][j][r] * invT);
            s += __shfl_xor(s, 1); s += __shfl_xor(s, 2);
            s += __shfl_xor(s, 4); s += __shfl_xor(s, 8);
            if (lrow == 0) atomicAdd(&rowred[wr * 64 + i * 16 + quad * 4 + r], s);
        }
    }
    __syncthreads();
    if (t < 128) atomicAdd(&sumexp[row0 + t], rowred[t]);
}

__global__ __launch_bounds__(256) void final_loss(const float* __restrict__ pos,
                                                  const float* __restrict__ sumexp,
                                                  float* __restrict__ out, int B_) {
    const int t = threadIdx.x;
    float acc = 0.f;
    for (int i = t; i < B_; i += 256) acc += logf(sumexp[i]) - pos[i];
    __shared__ float s[256];
    s[t] = acc;
    __syncthreads();
    for (int off = 128; off > 0; off >>= 1) {
        if (t < off) s[t] += s[t + off];
        __syncthreads();
    }
    if (t == 0) out[0] = s[0] / (float)B_;
}

extern "C" void kernel_launch(void* const* d_in, const int* in_sizes, int n_in,
                              void* d_out, int out_size, void* d_ws, size_t ws_size,
                              hipStream_t stream) {
    const float* y1    = (const float*)d_in[0];
    const float* y2    = (const float*)d_in[1];
    const float* Wq    = (const float*)d_in[2];
    const float* Wk    = (const float*)d_in[3];
    const float* Wp    = (const float*)d_in[4];
    const float* queue = (const float*)d_in[5];
    const int*   sidx  = (const int*)d_in[6];
    const int*   widx  = (const int*)d_in[7];
    float* out = (float*)d_out;

    const int B    = in_sizes[7];              // 1024
    const int NNEG = in_sizes[6];              // 16384
    const int D    = in_sizes[0] / B;          // 2048
    const int H    = in_sizes[2] / D;          // 1024
    const int M    = in_sizes[4] / H;          // 256
    const float invT = 1.0f / 0.07f;
    const int NS_P = 4;

    // ---- workspace layout (identical to R4..R11, which passed) ----
    float* ws  = (float*)d_ws;
    float* Pp     = ws;                              // [2*NS_P][B*M] = 2M floats
    float* pos    = Pp + (size_t)2 * NS_P * B * M;
    float* sumexp = pos + B;
    unsigned short* us = (unsigned short*)(sumexp + B);
    unsigned short* y2b  = us;                       // B*D   (y2b|y1b contiguous)
    unsigned short* y1b  = y2b + (size_t)B * D;      // B*D
    unsigned short* Wqb  = y1b + (size_t)B * D;      // D*H   (Wqb|Wkb contiguous)
    unsigned short* Wkb  = Wqb + (size_t)D * H;      // D*H
    unsigned short* Wpt  = Wkb + (size_t)D * H;      // M*H
    unsigned short* Wct  = Wpt + (size_t)M * H;      // [2][M][D] bf16
    unsigned short* qkb  = Wct + (size_t)2 * M * D;  // 2*B*M
    unsigned short* negb = qkb + (size_t)2 * B * M;  // NNEG*M

    // 1. all streaming work: casts + transpose + gather + dword queue copy
    const int nPrep = 4 * 1024 + (H / 32) * (M / 32) + NNEG / 64 + 2048;
    prep_all<<<nPrep, 256, 0, stream>>>(y2, y1, Wq, Wk, Wp,
                                        y2b, y1b, Wqb, Wkb, Wpt,
                                        queue, sidx, negb, out + 1,
                                        D, H, M);

    // 2. Wc^T GEMM, uncontended
    wc_gemm<<<128, 256, 0, stream>>>(Wpt, Wqb, Wct);

    // 3. qk projection GEMM (K-split 4, fp32 partials), pure
    qk_gemm<<<512, 256, 0, stream>>>(y2b, Wct, Pp);

    // 4. fused reduce + l2norm + cast + pos/sumexp + scatter k
    qk_finalize<<<B, 256, 0, stream>>>(Pp, widx, qkb, out + 1, pos, sumexp,
                                       B, NS_P, invT);

    // 5. fused negative logits + exp + row-sum
    gemm_logits<<<dim3(NNEG / 128, B / 128), 256, 0, stream>>>(
        qkb, negb, sumexp, M, invT);

    // 6. loss
    final_loss<<<1, 256, 0, stream>>>(pos, sumexp, out, B);
}